// Round 1
// baseline (1406.800 us; speedup 1.0000x reference)
//
#include <hip/hip_runtime.h>

#define NUSERS 100000
#define NITEMS 50000
#define DIM 64
#define NNZ 1600000
#define ALPHA 0.1f
#define TROWS (NUSERS + NITEMS)
#define LSTRIDE (TROWS * DIM)

// Layer 0 copy + alpha-init of layers 1 and 2.
__global__ __launch_bounds__(256) void init_out_kernel(const float4* __restrict__ ue,
                                                       const float4* __restrict__ ie,
                                                       float4* __restrict__ out) {
    const int nU4 = NUSERS * DIM / 4;   // 1.6M float4
    const int nT4 = TROWS * DIM / 4;    // 2.4M float4 per layer
    int i = blockIdx.x * 256 + threadIdx.x;
    if (i >= nT4) return;
    float4 v = (i < nU4) ? ue[i] : ie[i - nU4];
    out[i] = v;
    float4 a = make_float4(ALPHA * v.x, ALPHA * v.y, ALPHA * v.z, ALPHA * v.w);
    out[nT4 + i] = a;
    out[2 * nT4 + i] = a;
}

// One layer of propagation: both SpMMs (user<-item and item<-user) in one
// launch. Thread t handles (edge e = t>>6, dim d = t&63): wave-uniform edge
// metadata, coalesced 256B gather of x[col], coalesced atomic scatter to
// y[row].
__global__ __launch_bounds__(256) void spmm_layer_kernel(
    const int* __restrict__ ui_rows, const int* __restrict__ ui_cols,
    const float* __restrict__ ui_vals,
    const int* __restrict__ iu_rows, const int* __restrict__ iu_cols,
    const float* __restrict__ iu_vals,
    const float* __restrict__ x_items,   // source features for ui matrix (items)
    const float* __restrict__ x_users,   // source features for iu matrix (users)
    float* __restrict__ y_users,         // accumulates A_ui @ x_items
    float* __restrict__ y_items)         // accumulates A_iu @ x_users
{
    unsigned tid = blockIdx.x * 256u + threadIdx.x;
    unsigned d = tid & 63u;
    unsigned e = tid >> 6;
    if (e < NNZ) {
        int r = ui_rows[e];
        int c = ui_cols[e];
        float v = ui_vals[e];
        atomicAdd(&y_users[r * DIM + d], v * x_items[c * DIM + d]);
    } else {
        e -= NNZ;
        if (e < NNZ) {
            int r = iu_rows[e];
            int c = iu_cols[e];
            float v = iu_vals[e];
            atomicAdd(&y_items[r * DIM + d], v * x_users[c * DIM + d]);
        }
    }
}

extern "C" void kernel_launch(void* const* d_in, const int* in_sizes, int n_in,
                              void* d_out, int out_size, void* d_ws, size_t ws_size,
                              hipStream_t stream) {
    const float* ue      = (const float*)d_in[0];  // user_emb0 [100000,64]
    const float* ie      = (const float*)d_in[1];  // item_emb0 [50000,64]
    const float* ui_vals = (const float*)d_in[2];
    const float* iu_vals = (const float*)d_in[3];
    const int*   ui_rows = (const int*)d_in[4];
    const int*   ui_cols = (const int*)d_in[5];
    const int*   iu_rows = (const int*)d_in[6];
    const int*   iu_cols = (const int*)d_in[7];
    float* out = (float*)d_out;

    // 1) init all three layers
    const int nT4 = TROWS * DIM / 4;
    init_out_kernel<<<(nT4 + 255) / 256, 256, 0, stream>>>(
        (const float4*)ue, (const float4*)ie, (float4*)out);

    float* L1 = out + (size_t)LSTRIDE;
    float* L2 = out + (size_t)2 * LSTRIDE;
    float* u1 = L1;
    float* i1 = L1 + (size_t)NUSERS * DIM;
    float* u2 = L2;
    float* i2 = L2 + (size_t)NUSERS * DIM;

    const unsigned nblocks = (2u * NNZ * 64u) / 256u;  // 800000 blocks, exact cover

    // 2) layer 1: u1 += A_ui @ i0 ; i1 += A_iu @ u0   (x from original inputs)
    spmm_layer_kernel<<<nblocks, 256, 0, stream>>>(
        ui_rows, ui_cols, ui_vals, iu_rows, iu_cols, iu_vals,
        ie, ue, u1, i1);

    // 3) layer 2: u2 += A_ui @ i1 ; i2 += A_iu @ u1
    spmm_layer_kernel<<<nblocks, 256, 0, stream>>>(
        ui_rows, ui_cols, ui_vals, iu_rows, iu_cols, iu_vals,
        i1, u1, u2, i2);
}

// Round 2
// 648.122 us; speedup vs baseline: 2.1706x; 2.1706x over previous
//
#include <hip/hip_runtime.h>

#define NUSERS 100000
#define NITEMS 50000
#define DIM 64
#define NNZ 1600000
#define ALPHA 0.1f
#define TROWS (NUSERS + NITEMS)   // 150000 combined rows
#define LSTRIDE (TROWS * DIM)
#define NEDGES (2 * NNZ)          // 3.2M combined edges
#define NB_SCAN ((TROWS + 255) / 256)   // 586 scan blocks

// ---------------- layer-0 copy ----------------
__global__ __launch_bounds__(256) void init_copy_kernel(const float4* __restrict__ ue,
                                                        const float4* __restrict__ ie,
                                                        float4* __restrict__ out) {
    const int nU4 = NUSERS * DIM / 4;
    const int nT4 = TROWS * DIM / 4;
    int i = blockIdx.x * 256 + threadIdx.x;
    if (i >= nT4) return;
    out[i] = (i < nU4) ? ue[i] : ie[i - nU4];
}

// ---------------- CSR build ----------------
__global__ __launch_bounds__(256) void hist_kernel(const int* __restrict__ ui_rows,
                                                   const int* __restrict__ iu_rows,
                                                   int* __restrict__ counts) {
    int i = blockIdx.x * 256 + threadIdx.x;
    if (i < NNZ) {
        atomicAdd(&counts[ui_rows[i]], 1);
    } else {
        i -= NNZ;
        if (i < NNZ) atomicAdd(&counts[NUSERS + iu_rows[i]], 1);
    }
}

__global__ __launch_bounds__(256) void scan_block_kernel(const int* __restrict__ counts,
                                                         int* __restrict__ incl,
                                                         int* __restrict__ bsums) {
    __shared__ int s[256];
    int i = blockIdx.x * 256 + threadIdx.x;
    int t = threadIdx.x;
    s[t] = (i < TROWS) ? counts[i] : 0;
    __syncthreads();
    for (int off = 1; off < 256; off <<= 1) {
        int v = (t >= off) ? s[t - off] : 0;
        __syncthreads();
        s[t] += v;
        __syncthreads();
    }
    if (i < TROWS) incl[i] = s[t];
    if (t == 255) bsums[blockIdx.x] = s[255];
}

__global__ __launch_bounds__(1024) void scan_bsums_kernel(int* __restrict__ bsums, int nb) {
    __shared__ int s[1024];
    int t = threadIdx.x;
    s[t] = (t < nb) ? bsums[t] : 0;
    __syncthreads();
    for (int off = 1; off < 1024; off <<= 1) {
        int v = (t >= off) ? s[t - off] : 0;
        __syncthreads();
        s[t] += v;
        __syncthreads();
    }
    // write EXCLUSIVE offsets back
    if (t < nb) bsums[t] = (t > 0) ? s[t - 1] : 0;
}

__global__ __launch_bounds__(256) void finalize_rowptr_kernel(const int* __restrict__ incl,
                                                              const int* __restrict__ boffs,
                                                              int* __restrict__ rowptr) {
    int i = blockIdx.x * 256 + threadIdx.x;
    if (i < TROWS) rowptr[i + 1] = incl[i] + boffs[i >> 8];
    if (i == 0) rowptr[0] = 0;
}

__global__ __launch_bounds__(256) void scatter_kernel(
    const int* __restrict__ ui_rows, const int* __restrict__ ui_cols,
    const float* __restrict__ ui_vals,
    const int* __restrict__ iu_rows, const int* __restrict__ iu_cols,
    const float* __restrict__ iu_vals,
    const int* __restrict__ rowptr, int* __restrict__ cursor,
    int* __restrict__ ccols, float* __restrict__ cvals)
{
    int i = blockIdx.x * 256 + threadIdx.x;
    int row, col; float val;
    if (i < NNZ) {
        row = ui_rows[i]; col = ui_cols[i]; val = ui_vals[i];
    } else {
        i -= NNZ;
        if (i >= NNZ) return;
        row = NUSERS + iu_rows[i]; col = iu_cols[i]; val = iu_vals[i];
    }
    int pos = rowptr[row] + atomicAdd(&cursor[row], 1);
    ccols[pos] = col;
    cvals[pos] = val;
}

// ---------------- pull SpMM: one wave per output row ----------------
// Row r < NUSERS gathers from the item table (xi); otherwise from users (xu).
__global__ __launch_bounds__(256) void pull_kernel(
    const int* __restrict__ rowptr, const int* __restrict__ ccols,
    const float* __restrict__ cvals,
    const float* __restrict__ xu,    // source features, user table
    const float* __restrict__ xi,    // source features, item table
    const float* __restrict__ ue0, const float* __restrict__ ie0,
    float* __restrict__ outL)
{
    int gid = blockIdx.x * 256 + threadIdx.x;
    int r = gid >> 6;
    int lane = threadIdx.x & 63;
    if (r >= TROWS) return;

    const float* x;
    const float* e0;
    if (r < NUSERS) { x = xi; e0 = ue0 + r * DIM; }
    else            { x = xu; e0 = ie0 + (r - NUSERS) * DIM; }

    float acc = ALPHA * e0[lane];
    int e = rowptr[r];
    int end = rowptr[r + 1];
    // 4-deep pipeline: 4 independent gathers in flight per wave
    for (; e + 4 <= end; e += 4) {
        int c0 = ccols[e], c1 = ccols[e + 1], c2 = ccols[e + 2], c3 = ccols[e + 3];
        float v0 = cvals[e], v1 = cvals[e + 1], v2 = cvals[e + 2], v3 = cvals[e + 3];
        float x0 = x[c0 * DIM + lane];
        float x1 = x[c1 * DIM + lane];
        float x2 = x[c2 * DIM + lane];
        float x3 = x[c3 * DIM + lane];
        acc = fmaf(v0, x0, acc);
        acc = fmaf(v1, x1, acc);
        acc = fmaf(v2, x2, acc);
        acc = fmaf(v3, x3, acc);
    }
    for (; e < end; ++e)
        acc = fmaf(cvals[e], x[ccols[e] * DIM + lane], acc);

    outL[r * DIM + lane] = acc;
}

// ---------------- fallback (round-1 atomic path) ----------------
__global__ __launch_bounds__(256) void init_out_kernel(const float4* __restrict__ ue,
                                                       const float4* __restrict__ ie,
                                                       float4* __restrict__ out) {
    const int nU4 = NUSERS * DIM / 4;
    const int nT4 = TROWS * DIM / 4;
    int i = blockIdx.x * 256 + threadIdx.x;
    if (i >= nT4) return;
    float4 v = (i < nU4) ? ue[i] : ie[i - nU4];
    out[i] = v;
    float4 a = make_float4(ALPHA * v.x, ALPHA * v.y, ALPHA * v.z, ALPHA * v.w);
    out[nT4 + i] = a;
    out[2 * nT4 + i] = a;
}

__global__ __launch_bounds__(256) void spmm_layer_kernel(
    const int* __restrict__ ui_rows, const int* __restrict__ ui_cols,
    const float* __restrict__ ui_vals,
    const int* __restrict__ iu_rows, const int* __restrict__ iu_cols,
    const float* __restrict__ iu_vals,
    const float* __restrict__ x_items, const float* __restrict__ x_users,
    float* __restrict__ y_users, float* __restrict__ y_items)
{
    unsigned tid = blockIdx.x * 256u + threadIdx.x;
    unsigned d = tid & 63u;
    unsigned e = tid >> 6;
    if (e < NNZ) {
        int r = ui_rows[e];
        int c = ui_cols[e];
        float v = ui_vals[e];
        atomicAdd(&y_users[r * DIM + d], v * x_items[c * DIM + d]);
    } else {
        e -= NNZ;
        if (e < NNZ) {
            int r = iu_rows[e];
            int c = iu_cols[e];
            float v = iu_vals[e];
            atomicAdd(&y_items[r * DIM + d], v * x_users[c * DIM + d]);
        }
    }
}

extern "C" void kernel_launch(void* const* d_in, const int* in_sizes, int n_in,
                              void* d_out, int out_size, void* d_ws, size_t ws_size,
                              hipStream_t stream) {
    const float* ue      = (const float*)d_in[0];
    const float* ie      = (const float*)d_in[1];
    const float* ui_vals = (const float*)d_in[2];
    const float* iu_vals = (const float*)d_in[3];
    const int*   ui_rows = (const int*)d_in[4];
    const int*   ui_cols = (const int*)d_in[5];
    const int*   iu_rows = (const int*)d_in[6];
    const int*   iu_cols = (const int*)d_in[7];
    float* out = (float*)d_out;

    float* L1 = out + (size_t)LSTRIDE;
    float* L2 = out + (size_t)2 * LSTRIDE;

    // workspace layout (ints): counts[150016] cursor[150016] rowptr[150016]
    //                          bsums[1024] ccols[NEDGES] cvals[NEDGES]
    const size_t RPAD = 150016;
    size_t need_ints = RPAD * 3 + 1024 + (size_t)NEDGES * 2;
    size_t need_bytes = need_ints * 4;

    if (ws_size < need_bytes) {
        // fallback: atomic scatter path (round-1, known-good)
        const int nT4 = TROWS * DIM / 4;
        init_out_kernel<<<(nT4 + 255) / 256, 256, 0, stream>>>(
            (const float4*)ue, (const float4*)ie, (float4*)out);
        float* u1 = L1; float* i1 = L1 + (size_t)NUSERS * DIM;
        float* u2 = L2; float* i2 = L2 + (size_t)NUSERS * DIM;
        const unsigned nblocks = (2u * NNZ * 64u) / 256u;
        spmm_layer_kernel<<<nblocks, 256, 0, stream>>>(
            ui_rows, ui_cols, ui_vals, iu_rows, iu_cols, iu_vals, ie, ue, u1, i1);
        spmm_layer_kernel<<<nblocks, 256, 0, stream>>>(
            ui_rows, ui_cols, ui_vals, iu_rows, iu_cols, iu_vals, i1, u1, u2, i2);
        return;
    }

    int* counts = (int*)d_ws;
    int* cursor = counts + RPAD;
    int* rowptr = cursor + RPAD;
    int* bsums  = rowptr + RPAD;
    int* ccols  = bsums + 1024;
    float* cvals = (float*)(ccols + NEDGES);

    // zero counts + cursor in one shot (they are adjacent)
    hipMemsetAsync(counts, 0, RPAD * 2 * sizeof(int), stream);

    // layer 0 copy (independent of CSR build)
    const int nT4 = TROWS * DIM / 4;
    init_copy_kernel<<<(nT4 + 255) / 256, 256, 0, stream>>>(
        (const float4*)ue, (const float4*)ie, (float4*)out);

    // CSR build
    const int egrid = (NEDGES + 255) / 256;
    hist_kernel<<<egrid, 256, 0, stream>>>(ui_rows, iu_rows, counts);
    scan_block_kernel<<<NB_SCAN, 256, 0, stream>>>(counts, counts /*in-place incl*/, bsums);
    scan_bsums_kernel<<<1, 1024, 0, stream>>>(bsums, NB_SCAN);
    finalize_rowptr_kernel<<<NB_SCAN, 256, 0, stream>>>(counts, bsums, rowptr);
    scatter_kernel<<<egrid, 256, 0, stream>>>(
        ui_rows, ui_cols, ui_vals, iu_rows, iu_cols, iu_vals,
        rowptr, cursor, ccols, cvals);

    // pull layers
    const int pgrid = (TROWS * DIM) / 256;   // 37500 blocks
    float* u1 = L1; float* i1 = L1 + (size_t)NUSERS * DIM;
    pull_kernel<<<pgrid, 256, 0, stream>>>(
        rowptr, ccols, cvals, ue, ie, ue, ie, L1);
    pull_kernel<<<pgrid, 256, 0, stream>>>(
        rowptr, ccols, cvals, u1, i1, ue, ie, L2);
}

// Round 3
// 563.863 us; speedup vs baseline: 2.4949x; 1.1494x over previous
//
#include <hip/hip_runtime.h>

#define NUSERS 100000
#define NITEMS 50000
#define DIM 64
#define NNZ 1600000
#define ALPHA 0.1f
#define TROWS (NUSERS + NITEMS)   // 150000 combined rows
#define LSTRIDE (TROWS * DIM)
#define NEDGES (2 * NNZ)          // 3.2M combined edges
#define NB_SCAN ((TROWS + 255) / 256)   // 586 scan blocks

// ---------------- layer-0 copy ----------------
__global__ __launch_bounds__(256) void init_copy_kernel(const float4* __restrict__ ue,
                                                        const float4* __restrict__ ie,
                                                        float4* __restrict__ out) {
    const int nU4 = NUSERS * DIM / 4;
    const int nT4 = TROWS * DIM / 4;
    int i = blockIdx.x * 256 + threadIdx.x;
    if (i >= nT4) return;
    out[i] = (i < nU4) ? ue[i] : ie[i - nU4];
}

// ---------------- CSR build ----------------
__global__ __launch_bounds__(256) void hist_kernel(const int* __restrict__ ui_rows,
                                                   const int* __restrict__ iu_rows,
                                                   int* __restrict__ counts) {
    int i = blockIdx.x * 256 + threadIdx.x;
    if (i < NNZ) {
        atomicAdd(&counts[ui_rows[i]], 1);
    } else {
        i -= NNZ;
        if (i < NNZ) atomicAdd(&counts[NUSERS + iu_rows[i]], 1);
    }
}

__global__ __launch_bounds__(256) void scan_block_kernel(const int* __restrict__ counts,
                                                         int* __restrict__ incl,
                                                         int* __restrict__ bsums) {
    __shared__ int s[256];
    int i = blockIdx.x * 256 + threadIdx.x;
    int t = threadIdx.x;
    s[t] = (i < TROWS) ? counts[i] : 0;
    __syncthreads();
    for (int off = 1; off < 256; off <<= 1) {
        int v = (t >= off) ? s[t - off] : 0;
        __syncthreads();
        s[t] += v;
        __syncthreads();
    }
    if (i < TROWS) incl[i] = s[t];
    if (t == 255) bsums[blockIdx.x] = s[255];
}

__global__ __launch_bounds__(1024) void scan_bsums_kernel(int* __restrict__ bsums, int nb) {
    __shared__ int s[1024];
    int t = threadIdx.x;
    s[t] = (t < nb) ? bsums[t] : 0;
    __syncthreads();
    for (int off = 1; off < 1024; off <<= 1) {
        int v = (t >= off) ? s[t - off] : 0;
        __syncthreads();
        s[t] += v;
        __syncthreads();
    }
    // write EXCLUSIVE offsets back
    if (t < nb) bsums[t] = (t > 0) ? s[t - 1] : 0;
}

__global__ __launch_bounds__(256) void finalize_rowptr_kernel(const int* __restrict__ incl,
                                                              const int* __restrict__ boffs,
                                                              int* __restrict__ rowptr) {
    int i = blockIdx.x * 256 + threadIdx.x;
    if (i < TROWS) rowptr[i + 1] = incl[i] + boffs[i >> 8];
    if (i == 0) rowptr[0] = 0;
}

// Scatter edges to row-sorted order. ONE 8B random write per edge (int2 of
// {col, val-bits}) instead of two 4B writes to separate arrays.
__global__ __launch_bounds__(256) void scatter_kernel(
    const int* __restrict__ ui_rows, const int* __restrict__ ui_cols,
    const float* __restrict__ ui_vals,
    const int* __restrict__ iu_rows, const int* __restrict__ iu_cols,
    const float* __restrict__ iu_vals,
    const int* __restrict__ rowptr, int* __restrict__ cursor,
    int2* __restrict__ cc)
{
    int i = blockIdx.x * 256 + threadIdx.x;
    int row, col; float val;
    if (i < NNZ) {
        row = ui_rows[i]; col = ui_cols[i]; val = ui_vals[i];
    } else {
        i -= NNZ;
        if (i >= NNZ) return;
        row = NUSERS + iu_rows[i]; col = iu_cols[i]; val = iu_vals[i];
    }
    int pos = rowptr[row] + atomicAdd(&cursor[row], 1);
    cc[pos] = make_int2(col, __float_as_int(val));
}

// ---------------- pull SpMM: one wave per output row ----------------
// Wave = 4 edge-groups x 16 lanes; each lane loads a float4 (group covers the
// full 256B feature row of its edge in one dwordx4). 2-deep unroll => 8
// independent gathers in flight per wave. Cross-group reduction via shfl_xor.
__global__ __launch_bounds__(256) void pull_kernel(
    const int* __restrict__ rowptr, const int2* __restrict__ cc,
    const float* __restrict__ xu,    // source features, user table
    const float* __restrict__ xi,    // source features, item table
    const float* __restrict__ ue0, const float* __restrict__ ie0,
    float* __restrict__ outL)
{
    int gid = blockIdx.x * 256 + threadIdx.x;
    int r = gid >> 6;
    if (r >= TROWS) return;
    int lane = threadIdx.x & 63;
    int g = lane >> 4;        // edge slot within wave: 0..3
    int sub = lane & 15;      // float4 index within feature row

    const float4* x;
    const float4* e0;
    if (r < NUSERS) { x = (const float4*)xi; e0 = (const float4*)(ue0 + (size_t)r * DIM); }
    else            { x = (const float4*)xu; e0 = (const float4*)(ie0 + (size_t)(r - NUSERS) * DIM); }

    float4 acc = make_float4(0.f, 0.f, 0.f, 0.f);
    int end = rowptr[r + 1];
    int e = rowptr[r] + g;

    // unrolled: edges e and e+4 per iteration (per group)
    for (; e + 4 < end; e += 8) {
        int2 m0 = cc[e];
        int2 m1 = cc[e + 4];
        float4 x0 = x[m0.x * 16 + sub];
        float4 x1 = x[m1.x * 16 + sub];
        float v0 = __int_as_float(m0.y);
        float v1 = __int_as_float(m1.y);
        acc.x = fmaf(v0, x0.x, acc.x);
        acc.y = fmaf(v0, x0.y, acc.y);
        acc.z = fmaf(v0, x0.z, acc.z);
        acc.w = fmaf(v0, x0.w, acc.w);
        acc.x = fmaf(v1, x1.x, acc.x);
        acc.y = fmaf(v1, x1.y, acc.y);
        acc.z = fmaf(v1, x1.z, acc.z);
        acc.w = fmaf(v1, x1.w, acc.w);
    }
    if (e < end) {
        int2 m0 = cc[e];
        float4 x0 = x[m0.x * 16 + sub];
        float v0 = __int_as_float(m0.y);
        acc.x = fmaf(v0, x0.x, acc.x);
        acc.y = fmaf(v0, x0.y, acc.y);
        acc.z = fmaf(v0, x0.z, acc.z);
        acc.w = fmaf(v0, x0.w, acc.w);
    }

    // reduce the 4 edge-groups: lanes {sub, sub+16, sub+32, sub+48}
    acc.x += __shfl_xor(acc.x, 16, 64);
    acc.y += __shfl_xor(acc.y, 16, 64);
    acc.z += __shfl_xor(acc.z, 16, 64);
    acc.w += __shfl_xor(acc.w, 16, 64);
    acc.x += __shfl_xor(acc.x, 32, 64);
    acc.y += __shfl_xor(acc.y, 32, 64);
    acc.z += __shfl_xor(acc.z, 32, 64);
    acc.w += __shfl_xor(acc.w, 32, 64);

    if (g == 0) {
        float4 b = e0[sub];
        acc.x = fmaf(ALPHA, b.x, acc.x);
        acc.y = fmaf(ALPHA, b.y, acc.y);
        acc.z = fmaf(ALPHA, b.z, acc.z);
        acc.w = fmaf(ALPHA, b.w, acc.w);
        ((float4*)(outL + (size_t)r * DIM))[sub] = acc;
    }
}

// ---------------- fallback (round-1 atomic path) ----------------
__global__ __launch_bounds__(256) void init_out_kernel(const float4* __restrict__ ue,
                                                       const float4* __restrict__ ie,
                                                       float4* __restrict__ out) {
    const int nU4 = NUSERS * DIM / 4;
    const int nT4 = TROWS * DIM / 4;
    int i = blockIdx.x * 256 + threadIdx.x;
    if (i >= nT4) return;
    float4 v = (i < nU4) ? ue[i] : ie[i - nU4];
    out[i] = v;
    float4 a = make_float4(ALPHA * v.x, ALPHA * v.y, ALPHA * v.z, ALPHA * v.w);
    out[nT4 + i] = a;
    out[2 * nT4 + i] = a;
}

__global__ __launch_bounds__(256) void spmm_layer_kernel(
    const int* __restrict__ ui_rows, const int* __restrict__ ui_cols,
    const float* __restrict__ ui_vals,
    const int* __restrict__ iu_rows, const int* __restrict__ iu_cols,
    const float* __restrict__ iu_vals,
    const float* __restrict__ x_items, const float* __restrict__ x_users,
    float* __restrict__ y_users, float* __restrict__ y_items)
{
    unsigned tid = blockIdx.x * 256u + threadIdx.x;
    unsigned d = tid & 63u;
    unsigned e = tid >> 6;
    if (e < NNZ) {
        int r = ui_rows[e];
        int c = ui_cols[e];
        float v = ui_vals[e];
        atomicAdd(&y_users[r * DIM + d], v * x_items[c * DIM + d]);
    } else {
        e -= NNZ;
        if (e < NNZ) {
            int r = iu_rows[e];
            int c = iu_cols[e];
            float v = iu_vals[e];
            atomicAdd(&y_items[r * DIM + d], v * x_users[c * DIM + d]);
        }
    }
}

extern "C" void kernel_launch(void* const* d_in, const int* in_sizes, int n_in,
                              void* d_out, int out_size, void* d_ws, size_t ws_size,
                              hipStream_t stream) {
    const float* ue      = (const float*)d_in[0];
    const float* ie      = (const float*)d_in[1];
    const float* ui_vals = (const float*)d_in[2];
    const float* iu_vals = (const float*)d_in[3];
    const int*   ui_rows = (const int*)d_in[4];
    const int*   ui_cols = (const int*)d_in[5];
    const int*   iu_rows = (const int*)d_in[6];
    const int*   iu_cols = (const int*)d_in[7];
    float* out = (float*)d_out;

    float* L1 = out + (size_t)LSTRIDE;
    float* L2 = out + (size_t)2 * LSTRIDE;

    // workspace layout (ints): counts[150016] cursor[150016] rowptr[150016]
    //                          bsums[1024] cc[NEDGES int2]
    const size_t RPAD = 150016;
    size_t need_bytes = (RPAD * 3 + 1024) * 4 + (size_t)NEDGES * 8;

    if (ws_size < need_bytes) {
        // fallback: atomic scatter path (round-1, known-good)
        const int nT4 = TROWS * DIM / 4;
        init_out_kernel<<<(nT4 + 255) / 256, 256, 0, stream>>>(
            (const float4*)ue, (const float4*)ie, (float4*)out);
        float* u1 = L1; float* i1 = L1 + (size_t)NUSERS * DIM;
        float* u2 = L2; float* i2 = L2 + (size_t)NUSERS * DIM;
        const unsigned nblocks = (2u * NNZ * 64u) / 256u;
        spmm_layer_kernel<<<nblocks, 256, 0, stream>>>(
            ui_rows, ui_cols, ui_vals, iu_rows, iu_cols, iu_vals, ie, ue, u1, i1);
        spmm_layer_kernel<<<nblocks, 256, 0, stream>>>(
            ui_rows, ui_cols, ui_vals, iu_rows, iu_cols, iu_vals, i1, u1, u2, i2);
        return;
    }

    int* counts = (int*)d_ws;
    int* cursor = counts + RPAD;
    int* rowptr = cursor + RPAD;
    int* bsums  = rowptr + RPAD;
    int2* cc    = (int2*)(bsums + 1024);   // offset 1804288 B, 8B-aligned

    // zero counts + cursor in one shot (they are adjacent)
    hipMemsetAsync(counts, 0, RPAD * 2 * sizeof(int), stream);

    // layer 0 copy (independent of CSR build)
    const int nT4 = TROWS * DIM / 4;
    init_copy_kernel<<<(nT4 + 255) / 256, 256, 0, stream>>>(
        (const float4*)ue, (const float4*)ie, (float4*)out);

    // CSR build
    const int egrid = (NEDGES + 255) / 256;
    hist_kernel<<<egrid, 256, 0, stream>>>(ui_rows, iu_rows, counts);
    scan_block_kernel<<<NB_SCAN, 256, 0, stream>>>(counts, counts /*in-place incl*/, bsums);
    scan_bsums_kernel<<<1, 1024, 0, stream>>>(bsums, NB_SCAN);
    finalize_rowptr_kernel<<<NB_SCAN, 256, 0, stream>>>(counts, bsums, rowptr);
    scatter_kernel<<<egrid, 256, 0, stream>>>(
        ui_rows, ui_cols, ui_vals, iu_rows, iu_cols, iu_vals,
        rowptr, cursor, cc);

    // pull layers
    const int pgrid = (TROWS * DIM) / 256;   // 37500 blocks
    float* u1 = L1; float* i1 = L1 + (size_t)NUSERS * DIM;
    pull_kernel<<<pgrid, 256, 0, stream>>>(
        rowptr, cc, ue, ie, ue, ie, L1);
    pull_kernel<<<pgrid, 256, 0, stream>>>(
        rowptr, cc, u1, i1, ue, ie, L2);
}